// Round 4
// baseline (299.260 us; speedup 1.0000x reference)
//
#include <hip/hip_runtime.h>
#include <cstdint>
#include <cstddef>

// Problem constants
#define Bb 64
#define Ss 197
#define Dd 768
#define Pp 196
// Dead code in reference: softmax over singleton axis -> attn==1 -> out = sampled_v.
// out[b,0,:]=1 ; out[b,1+p,:] = (sum_j w_j x[b,i_j,:]) @ Wv + (sum_j w_j) bv
// M = 12544 = 196 tiles x 64 rows, N = K = 768.
//
// Round-4: single persistent kernel. Grid 1024 = 4 blocks/CU guaranteed
// co-resident (__launch_bounds__(256,4) caps unified regs at 128 -> >=4
// waves/SIMD; LDS 24KB -> 6 blocks/CU). Phase 1: XCD-partitioned gather
// (block bid: xcd=bid&7 produces rows of m-tiles {xcd, xcd+8,...}) +
// per-XCD WvT replica transpose (no cross-XCD data flow at all) + cls.
// Epoch-based device-atomic grid barrier (spin capped: wrong assumptions
// fail visibly, never hang). Phase 2: 64x128 MFMA gemm, persistent loop
// over this XCD's tiles. Ag/wsB/WvT stay warm in the XCD's L2 (2.4+1.2MB
// slice < 4MB) -> no HBM round-trip, no second launch ramp.

typedef short bf16x8 __attribute__((ext_vector_type(8)));
typedef short bf16x4 __attribute__((ext_vector_type(4)));
typedef float f32x4  __attribute__((ext_vector_type(4)));
struct alignas(16) F4 { float v[4]; };

__device__ unsigned long long g_bar;   // zero at module load; epoch logic below

__device__ __forceinline__ int mod_s(int v) {
    int r = v % Ss;
    return (r < 0) ? r + Ss : r;   // Python/JAX % semantics
}

__device__ __forceinline__ unsigned short f2bf(float f) {
    union { float f; unsigned u; } v; v.f = f;
    unsigned r = (v.u + 0x7FFFu + ((v.u >> 16) & 1u)) >> 16;  // RNE
    return (unsigned short)r;
}

// async global->LDS DMA, 16B per lane; LDS dest = wave-uniform base + lane*16
__device__ __forceinline__ void gload_lds16(const void* g, void* l) {
    __builtin_amdgcn_global_load_lds(
        (const __attribute__((address_space(1))) unsigned int*)g,
        (__attribute__((address_space(3))) unsigned int*)l, 16, 0, 0);
}

struct GParams {
    float w0, w1, w2, w3;
    int i0, i1, i2, i3;
};

__device__ __forceinline__ GParams gather_params(
    const int* img_ids, const float* avgs, const float* stds,
    const float* noise, int b, int p)
{
    const int id = img_ids[b];
    const float a0 = avgs [((size_t)id * 2    ) * Pp + p];
    const float a1 = avgs [((size_t)id * 2 + 1) * Pp + p];
    const float s0 = stds [((size_t)id * 2    ) * Pp + p];
    const float s1 = stds [((size_t)id * 2 + 1) * Pp + p];
    const float nx = noise[((size_t)b  * 2    ) * Pp + p];
    const float ny = noise[((size_t)b  * 2 + 1) * Pp + p];
    const float kx = (nx - a0) / s0;
    const float ky = (ny - a1) / s1;
    const float cx = ceilf(kx),  fx = floorf(kx);
    const float cy = ceilf(ky),  fy = floorf(ky);
    const float dcx = 1.0f - fabsf(cx - kx);
    const float dfx = 1.0f - fabsf(fx - kx);
    const float dcy = 1.0f - fabsf(cy - ky);
    const float dfy = 1.0f - fabsf(fy - ky);
    GParams g;
    g.w0 = dcx * dcy;  g.w1 = dfx * dcy;  g.w2 = dcx * dfy;  g.w3 = dfx * dfy;
    g.i0 = mod_s((int)(14.0f * cy + cx));
    g.i1 = mod_s((int)(14.0f * cy + fx));
    g.i2 = mod_s((int)(14.0f * fy + cx));
    g.i3 = mod_s((int)(14.0f * fy + fx));
    return g;
}

#define GRID_BLKS 1024
#define NSTG 12

__global__ __launch_bounds__(256, 4) void gsa_fused(
    const float* __restrict__ x,
    const int*   __restrict__ img_ids,
    const float* __restrict__ Wv,
    const float* __restrict__ avgs,
    const float* __restrict__ stds,
    const float* __restrict__ noise,
    const float* __restrict__ bv,
    unsigned short* __restrict__ Ag,     // (M,K) bf16
    unsigned short* __restrict__ WvTrep, // 8 x (N,K) bf16 per-XCD replicas
    float* __restrict__ wsB,             // (M,)
    float* __restrict__ out)
{
    __shared__ short lds[12288];   // phase1: T[64][66] alias; phase2: A|B tiles

    const int t    = threadIdx.x;
    const int bid  = blockIdx.x;
    const int xcd  = bid & 7;      // blockIdx % 8 -> XCD (round-robin dispatch)
    const int j    = bid >> 3;     // 0..127 within this XCD
    const int lane = t & 63;
    const int w    = t >> 6;

    const int tilesM = (xcd < 4) ? 25 : 24;   // m-tiles owned by this XCD (196 total)
    const int rowsX  = tilesM * 64;           // 1600 or 1536 gathered rows

    // ================= phase 1a: gather 13 rows into Ag (bf16) =================
    // Block j owns rows [j*13, j*13+13) of this XCD's row list; wave w takes
    // s = w, w+4, w+8, w+12.
    #pragma unroll
    for (int sidx = 0; sidx < 4; ++sidx) {
        const int s = w + sidx * 4;
        if (s >= 13) continue;                  // wave-uniform
        const int r = j * 13 + s;
        if (r >= rowsX) continue;
        const int tile = (r >> 6) * 8 + xcd;
        const int m    = tile * 64 + (r & 63);
        const int b    = m / Pp;
        const int p    = m - b * Pp;
        GParams g = gather_params(img_ids, avgs, stds, noise, b, p);
        const size_t xb = (size_t)b * Ss;
        const float* r0 = x + (xb + g.i0) * Dd;
        const float* r1 = x + (xb + g.i1) * Dd;
        const float* r2 = x + (xb + g.i2) * Dd;
        const float* r3 = x + (xb + g.i3) * Dd;
        unsigned short* dst = Ag + (size_t)m * Dd;
        #pragma unroll
        for (int c = 0; c < 3; ++c) {
            const int k = c * 256 + lane * 4;
            F4 v0 = *reinterpret_cast<const F4*>(r0 + k);
            F4 v1 = *reinterpret_cast<const F4*>(r1 + k);
            F4 v2 = *reinterpret_cast<const F4*>(r2 + k);
            F4 v3 = *reinterpret_cast<const F4*>(r3 + k);
            bf16x4 o;
            #pragma unroll
            for (int q = 0; q < 4; ++q)
                o[q] = (short)f2bf(g.w0*v0.v[q] + g.w1*v1.v[q] + g.w2*v2.v[q] + g.w3*v3.v[q]);
            *reinterpret_cast<bf16x4*>(dst + k) = o;
        }
        if (lane == 0) wsB[m] = g.w0 + g.w1 + g.w2 + g.w3;
    }

    // ============ phase 1b: Wv -> this XCD's WvT replica (144 64x64 tiles) ============
    unsigned short* rep = WvTrep + (size_t)xcd * Dd * Dd;
    {
        short (*T)[66] = reinterpret_cast<short(*)[66]>(lds);
        const int tx = t & 63, tyy = t >> 6;
        for (int tt = j; tt < 144; tt += 128) {   // j<16 blocks do a 2nd tile
            const int k0 = (tt % 12) * 64;
            const int n0 = (tt / 12) * 64;
            __syncthreads();
            #pragma unroll
            for (int pass = 0; pass < 16; ++pass) {
                const int i = pass * 4 + tyy;
                T[i][tx] = (short)f2bf(Wv[(size_t)(k0 + i) * Dd + n0 + tx]);
            }
            __syncthreads();
            #pragma unroll
            for (int pass = 0; pass < 16; ++pass) {
                const int n = pass * 4 + tyy;
                rep[(size_t)(n0 + n) * Dd + k0 + tx] = (unsigned short)T[tx][n];
            }
        }
    }

    // ================= phase 1c: cls rows (first 192 blocks) =================
    if (bid < 192) {
        const int idx = bid * 256 + t;            // < 49152 = 64*768
        const int b = idx / Dd;
        const int d = idx - b * Dd;
        out[(size_t)b * Ss * Dd + d] = 1.0f;
    }

    // ================= grid barrier (epoch-based, capped spin) =================
    __syncthreads();   // block's stores drained to L2 (vmcnt 0 before s_barrier)
    if (t == 0) {
        const unsigned long long old =
            __hip_atomic_fetch_add(&g_bar, 1ull, __ATOMIC_RELAXED,
                                   __HIP_MEMORY_SCOPE_AGENT);
        const unsigned long long target = (old / GRID_BLKS + 1ull) * GRID_BLKS;
        int guard = 0;
        while (__hip_atomic_load(&g_bar, __ATOMIC_RELAXED,
                                 __HIP_MEMORY_SCOPE_AGENT) < target) {
            __builtin_amdgcn_s_sleep(8);
            if (++guard > 400000) break;   // ~40ms: fail visibly, never hang
        }
    }
    __syncthreads();
    __builtin_amdgcn_fence(__ATOMIC_ACQUIRE, "workgroup");  // compiler ordering

    // ================= phase 2: 64x128 MFMA gemm over this XCD's tiles =================
    // MFMA fragment offsets (swizzle-aware), tile-independent.
    const int col  = lane & 15;
    const int quad = lane >> 4;
    const int wm   = (w & 1) * 32;      // wave's m-offset within 64
    const int wn   = (w >> 1) * 64;     // wave's n-offset within 128
    int offA[2][2], offB[4][2];
    #pragma unroll
    for (int i = 0; i < 2; ++i) {
        const int ra = wm + i * 16 + col;
        #pragma unroll
        for (int ks = 0; ks < 2; ++ks)
            offA[i][ks] = (ra * 8 + ((ks * 4 + quad) ^ (ra & 7))) * 8;
    }
    #pragma unroll
    for (int i = 0; i < 4; ++i) {
        const int rb = wn + i * 16 + col;
        #pragma unroll
        for (int ks = 0; ks < 2; ++ks)
            offB[i][ks] = 4096 + (rb * 8 + ((ks * 4 + quad) ^ (rb & 7))) * 8;
    }

    for (int u = j; u < tilesM * 6; u += 128) {   // 1-2 tiles per block
        const int n_t    = u % 6;
        const int mchunk = u / 6;
        const int m_tile = mchunk * 8 + xcd;
        const int m0 = m_tile * 64;
        const int n0 = n_t * 128;

        // staging: per wave 2 A-insts + 4 B-insts of 1KB each
        const unsigned short* aSrc[2];
        const unsigned short* bSrc[4];
        int ldsA[2], ldsB[4];
        #pragma unroll
        for (int i = 0; i < 2; ++i) {
            const int rr = (w * 2 + i) * 8 + (lane >> 3);   // A row 0..63
            const int qq = (lane & 7) ^ (rr & 7);
            aSrc[i] = Ag + (size_t)(m0 + rr) * Dd + qq * 8;
            ldsA[i] = (w * 2 + i) * 512;                    // shorts, wave-uniform
        }
        #pragma unroll
        for (int i = 0; i < 4; ++i) {
            const int rr = (w * 4 + i) * 8 + (lane >> 3);   // B row 0..127
            const int qq = (lane & 7) ^ (rr & 7);
            bSrc[i] = rep + (size_t)(n0 + rr) * Dd + qq * 8;
            ldsB[i] = 4096 + (w * 4 + i) * 512;
        }

        f32x4 acc[2][4];
        #pragma unroll
        for (int i = 0; i < 2; ++i)
            #pragma unroll
            for (int jj = 0; jj < 4; ++jj) acc[i][jj] = (f32x4)0.0f;

        for (int s = 0; s < NSTG; ++s) {
            const int kadv = s * 64;
            __syncthreads();              // prior LDS reads complete before overwrite
            #pragma unroll
            for (int i = 0; i < 2; ++i) gload_lds16(aSrc[i] + kadv, &lds[ldsA[i]]);
            #pragma unroll
            for (int i = 0; i < 4; ++i) gload_lds16(bSrc[i] + kadv, &lds[ldsB[i]]);
            __syncthreads();              // drains DMA (vmcnt 0) -> tile resident
            #pragma unroll
            for (int ks = 0; ks < 2; ++ks) {
                bf16x8 aF[2], bF[4];
                #pragma unroll
                for (int mi = 0; mi < 2; ++mi)
                    aF[mi] = *reinterpret_cast<const bf16x8*>(lds + offA[mi][ks]);
                #pragma unroll
                for (int ni = 0; ni < 4; ++ni)
                    bF[ni] = *reinterpret_cast<const bf16x8*>(lds + offB[ni][ks]);
                #pragma unroll
                for (int mi = 0; mi < 2; ++mi)
                    #pragma unroll
                    for (int ni = 0; ni < 4; ++ni)
                        acc[mi][ni] = __builtin_amdgcn_mfma_f32_16x16x32_bf16(
                            aF[mi], bF[ni], acc[mi][ni], 0, 0, 0);
            }
        }

        // epilogue
        float bvv[4];
        #pragma unroll
        for (int ni = 0; ni < 4; ++ni) bvv[ni] = bv[n0 + wn + ni * 16 + col];

        #pragma unroll
        for (int mi = 0; mi < 2; ++mi) {
            #pragma unroll
            for (int rg = 0; rg < 4; ++rg) {
                const int mg = m0 + wm + mi * 16 + quad * 4 + rg;
                const int b  = mg / Pp;
                const float wsv = wsB[mg];
                float* orow = out + ((size_t)(mg + b + 1)) * Dd;   // b*197 + 1 + p
                #pragma unroll
                for (int ni = 0; ni < 4; ++ni)
                    orow[n0 + wn + ni * 16 + col] = acc[mi][ni][rg] + wsv * bvv[ni];
            }
        }
    }
}

extern "C" void kernel_launch(void* const* d_in, const int* in_sizes, int n_in,
                              void* d_out, int out_size, void* d_ws, size_t ws_size,
                              hipStream_t stream) {
    // order: x, img_ids, mask, Wq, bq, Wk, bk, Wv, bv, avgs, std_devs, noise
    const float* x       = (const float*)d_in[0];
    const int*   img_ids = (const int*)  d_in[1];
    const float* Wv      = (const float*)d_in[7];
    const float* bv      = (const float*)d_in[8];
    const float* avgs    = (const float*)d_in[9];
    const float* stds    = (const float*)d_in[10];
    const float* noise   = (const float*)d_in[11];
    float* out = (float*)d_out;

    // ws layout (~28.8 MB of the ~313 MB workspace; fully rewritten each launch):
    const size_t ag_bytes  = (size_t)Bb * Pp * Dd * sizeof(unsigned short);     // 19.27 MB
    const size_t rep_bytes = (size_t)8 * Dd * Dd * sizeof(unsigned short);      //  9.44 MB
    unsigned short* Ag     = (unsigned short*)d_ws;
    unsigned short* WvTrep = (unsigned short*)((char*)d_ws + ag_bytes);
    float*          wsB    = (float*)((char*)d_ws + ag_bytes + rep_bytes);

    gsa_fused<<<GRID_BLKS, 256, 0, stream>>>(
        x, img_ids, Wv, avgs, stds, noise, bv, Ag, WvTrep, wsB, out);
}

// Round 5
// 212.377 us; speedup vs baseline: 1.4091x; 1.4091x over previous
//
#include <hip/hip_runtime.h>
#include <cstdint>
#include <cstddef>

// Problem constants
#define Bb 64
#define Ss 197
#define Dd 768
#define Pp 196
// Dead code in reference: softmax over singleton axis -> attn==1 -> out = sampled_v.
// out[b,0,:]=1 ; out[b,1+p,:] = (sum_j w_j x[b,i_j,:]) @ Wv + (sum_j w_j) bv
// M = 12544, N = K = 768.
//
// Round-5: exact revert to the round-3 two-kernel structure (best verified:
// 211.56 us). Round-4's fused persistent kernel regressed +88 us: the grid
// barrier serialized phase imbalance (MfmaUtil 5%, VALUBusy 8%, hbm 12% --
// everything idle) even though its L2 locality plan worked. The two-kernel
// launch-pipelined structure is the measured optimum.

typedef short bf16x8 __attribute__((ext_vector_type(8)));
typedef short bf16x4 __attribute__((ext_vector_type(4)));
typedef float f32x4  __attribute__((ext_vector_type(4)));
struct alignas(16) F4 { float v[4]; };

__device__ __forceinline__ int mod_s(int v) {
    int r = v % Ss;
    return (r < 0) ? r + Ss : r;   // Python/JAX % semantics
}

__device__ __forceinline__ unsigned short f2bf(float f) {
    union { float f; unsigned u; } v; v.f = f;
    unsigned r = (v.u + 0x7FFFu + ((v.u >> 16) & 1u)) >> 16;  // RNE
    return (unsigned short)r;
}

// async global->LDS DMA, 16B per lane; LDS dest = wave-uniform base + lane*16
__device__ __forceinline__ void gload_lds16(const void* g, void* l) {
    __builtin_amdgcn_global_load_lds(
        (const __attribute__((address_space(1))) unsigned int*)g,
        (__attribute__((address_space(3))) unsigned int*)l, 16, 0, 0);
}

struct GParams {
    float w0, w1, w2, w3;
    int i0, i1, i2, i3;
};

__device__ __forceinline__ GParams gather_params(
    const int* img_ids, const float* avgs, const float* stds,
    const float* noise, int b, int p)
{
    const int id = img_ids[b];
    const float a0 = avgs [((size_t)id * 2    ) * Pp + p];
    const float a1 = avgs [((size_t)id * 2 + 1) * Pp + p];
    const float s0 = stds [((size_t)id * 2    ) * Pp + p];
    const float s1 = stds [((size_t)id * 2 + 1) * Pp + p];
    const float nx = noise[((size_t)b  * 2    ) * Pp + p];
    const float ny = noise[((size_t)b  * 2 + 1) * Pp + p];
    const float kx = (nx - a0) / s0;
    const float ky = (ny - a1) / s1;
    const float cx = ceilf(kx),  fx = floorf(kx);
    const float cy = ceilf(ky),  fy = floorf(ky);
    const float dcx = 1.0f - fabsf(cx - kx);
    const float dfx = 1.0f - fabsf(fx - kx);
    const float dcy = 1.0f - fabsf(cy - ky);
    const float dfy = 1.0f - fabsf(fy - ky);
    GParams g;
    g.w0 = dcx * dcy;  g.w1 = dfx * dcy;  g.w2 = dcx * dfy;  g.w3 = dfx * dfy;
    g.i0 = mod_s((int)(14.0f * cy + cx));
    g.i1 = mod_s((int)(14.0f * cy + fx));
    g.i2 = mod_s((int)(14.0f * fy + cx));
    g.i3 = mod_s((int)(14.0f * fy + fx));
    return g;
}

// ================= prep: gather->Ag (bf16), Wv->WvT (bf16), cls rows =================
#define GATHER_BLKS 3328
#define TRANS_BLKS  144

__global__ __launch_bounds__(256) void gsa_prep(
    const float* __restrict__ x,
    const int*   __restrict__ img_ids,
    const float* __restrict__ Wv,
    const float* __restrict__ avgs,
    const float* __restrict__ stds,
    const float* __restrict__ noise,
    unsigned short* __restrict__ Ag,    // (M,K) bf16
    unsigned short* __restrict__ WvT,   // (N,K) bf16
    float* __restrict__ wsB,            // (M,)
    float* __restrict__ out)
{
    __shared__ short T[64][66];
    const int t   = threadIdx.x;
    const int blk = blockIdx.x;

    if (blk < GATHER_BLKS) {
        const int xcd  = blk & 7;
        const int s    = blk >> 3;       // 0..415
        const int tl   = s >> 5;         // 0..12
        const int r    = s & 31;
        const int tile = tl * 8 + xcd;
        if (tile < 98) {
            const int lane = t & 63;
            const int w    = t >> 6;
            const int m    = tile * 128 + r * 4 + w;
            const int b    = m / Pp;
            const int p    = m - b * Pp;
            GParams g = gather_params(img_ids, avgs, stds, noise, b, p);
            const size_t xb = (size_t)b * Ss;
            const float* r0 = x + (xb + g.i0) * Dd;
            const float* r1 = x + (xb + g.i1) * Dd;
            const float* r2 = x + (xb + g.i2) * Dd;
            const float* r3 = x + (xb + g.i3) * Dd;
            unsigned short* dst = Ag + (size_t)m * Dd;
            #pragma unroll
            for (int c = 0; c < 3; ++c) {
                const int k = c * 256 + lane * 4;
                F4 v0 = *reinterpret_cast<const F4*>(r0 + k);
                F4 v1 = *reinterpret_cast<const F4*>(r1 + k);
                F4 v2 = *reinterpret_cast<const F4*>(r2 + k);
                F4 v3 = *reinterpret_cast<const F4*>(r3 + k);
                bf16x4 o;
                #pragma unroll
                for (int q = 0; q < 4; ++q)
                    o[q] = (short)f2bf(g.w0*v0.v[q] + g.w1*v1.v[q] + g.w2*v2.v[q] + g.w3*v3.v[q]);
                *reinterpret_cast<bf16x4*>(dst + k) = o;
            }
            if (lane == 0) wsB[m] = g.w0 + g.w1 + g.w2 + g.w3;
        } else {
            // tiles 98..103 -> 192 spare blocks do cls rows (192*256 = 64*768)
            const int cb  = (xcd - 2) * 32 + r;       // 0..191
            const int idx = cb * 256 + t;             // < 49152
            const int b = idx / Dd;
            const int d = idx - b * Dd;
            out[(size_t)b * Ss * Dd + d] = 1.0f;
        }
    } else {
        const int tb = blk - GATHER_BLKS;          // 12x12 tiles of 64x64
        const int k0 = (tb % 12) * 64;
        const int n0 = (tb / 12) * 64;
        const int tx = t & 63, tyy = t >> 6;
        #pragma unroll
        for (int pass = 0; pass < 16; ++pass) {
            const int i = pass * 4 + tyy;
            T[i][tx] = (short)f2bf(Wv[(size_t)(k0 + i) * Dd + n0 + tx]);
        }
        __syncthreads();
        #pragma unroll
        for (int pass = 0; pass < 16; ++pass) {
            const int n = pass * 4 + tyy;
            WvT[(size_t)(n0 + n) * Dd + k0 + tx] = (unsigned short)T[tx][n];
        }
    }
}

// ===== MFMA GEMM: 64x128 tile, BK=64, single-buffer global_load_lds =====
// 256 thr / 4 waves (2m x 2n of 32x64). 12 stages, 2 barriers/stage.
// LDS 24KB: A = 64x64 bf16 [0,4096) shorts, B = 128x64 bf16 [4096,12288).
// Chunk swizzle: 16B chunk q of row r stored at slot r*8 + (q ^ (r&7)).
// Grid 1200 = 8 xcds * 25 mchunks * 6 n; m_tile = mchunk*8+xcd (24 idle).
#define NSTG 12

__global__ __launch_bounds__(256, 6) void gsa_gemm5(
    const unsigned short* __restrict__ Ag,    // (M,K)
    const unsigned short* __restrict__ WvT,   // (N,K)
    const float* __restrict__ wsB,
    const float* __restrict__ bv,
    float* __restrict__ out)
{
    __shared__ short lds[12288];   // A = [0,4096), B = [4096,12288)  (shorts)

    const int t = threadIdx.x;
    const int L      = blockIdx.x;
    const int xcd    = L & 7;
    const int grp    = L >> 3;          // 0..149
    const int n_t    = grp % 6;
    const int mchunk = grp / 6;         // 0..24
    const int m_tile = mchunk * 8 + xcd;
    if (m_tile >= 196) return;          // 24 of 1200 blocks idle
    const int m0 = m_tile * 64;
    const int n0 = n_t * 128;

    const int lane = t & 63;
    const int w    = t >> 6;

    // ---- staging: per wave 2 A-insts + 4 B-insts of 1KB each ----
    const unsigned short* aSrc[2];
    const unsigned short* bSrc[4];
    int ldsA[2], ldsB[4];
    #pragma unroll
    for (int i = 0; i < 2; ++i) {
        const int rr = (w * 2 + i) * 8 + (lane >> 3);   // A row 0..63
        const int qq = (lane & 7) ^ (rr & 7);
        aSrc[i] = Ag + (size_t)(m0 + rr) * Dd + qq * 8;
        ldsA[i] = (w * 2 + i) * 512;                    // shorts, wave-uniform
    }
    #pragma unroll
    for (int i = 0; i < 4; ++i) {
        const int rr = (w * 4 + i) * 8 + (lane >> 3);   // B row 0..127
        const int qq = (lane & 7) ^ (rr & 7);
        bSrc[i] = WvT + (size_t)(n0 + rr) * Dd + qq * 8;
        ldsB[i] = 4096 + (w * 4 + i) * 512;
    }

    // ---- MFMA fragment offsets (swizzle-aware) ----
    const int col  = lane & 15;
    const int quad = lane >> 4;
    const int wm   = (w & 1) * 32;      // wave's m-offset within 64
    const int wn   = (w >> 1) * 64;     // wave's n-offset within 128
    int offA[2][2], offB[4][2];
    #pragma unroll
    for (int i = 0; i < 2; ++i) {
        const int ra = wm + i * 16 + col;
        #pragma unroll
        for (int ks = 0; ks < 2; ++ks)
            offA[i][ks] = (ra * 8 + ((ks * 4 + quad) ^ (ra & 7))) * 8;
    }
    #pragma unroll
    for (int i = 0; i < 4; ++i) {
        const int rb = wn + i * 16 + col;
        #pragma unroll
        for (int ks = 0; ks < 2; ++ks)
            offB[i][ks] = 4096 + (rb * 8 + ((ks * 4 + quad) ^ (rb & 7))) * 8;
    }

    f32x4 acc[2][4];
    #pragma unroll
    for (int i = 0; i < 2; ++i)
        #pragma unroll
        for (int j = 0; j < 4; ++j) acc[i][j] = (f32x4)0.0f;

    for (int s = 0; s < NSTG; ++s) {
        const int kadv = s * 64;
        if (s > 0) __syncthreads();   // prior stage's LDS reads complete before overwrite
        #pragma unroll
        for (int i = 0; i < 2; ++i) gload_lds16(aSrc[i] + kadv, &lds[ldsA[i]]);
        #pragma unroll
        for (int i = 0; i < 4; ++i) gload_lds16(bSrc[i] + kadv, &lds[ldsB[i]]);
        __syncthreads();              // drains DMA (vmcnt 0) -> tile resident
        #pragma unroll
        for (int ks = 0; ks < 2; ++ks) {
            bf16x8 aF[2], bF[4];
            #pragma unroll
            for (int mi = 0; mi < 2; ++mi)
                aF[mi] = *reinterpret_cast<const bf16x8*>(lds + offA[mi][ks]);
            #pragma unroll
            for (int ni = 0; ni < 4; ++ni)
                bF[ni] = *reinterpret_cast<const bf16x8*>(lds + offB[ni][ks]);
            #pragma unroll
            for (int mi = 0; mi < 2; ++mi)
                #pragma unroll
                for (int ni = 0; ni < 4; ++ni)
                    acc[mi][ni] = __builtin_amdgcn_mfma_f32_16x16x32_bf16(
                        aF[mi], bF[ni], acc[mi][ni], 0, 0, 0);
        }
    }

    // ---- epilogue ----
    float bvv[4];
    #pragma unroll
    for (int ni = 0; ni < 4; ++ni) bvv[ni] = bv[n0 + wn + ni * 16 + col];

    #pragma unroll
    for (int mi = 0; mi < 2; ++mi) {
        #pragma unroll
        for (int rg = 0; rg < 4; ++rg) {
            const int mg = m0 + wm + mi * 16 + quad * 4 + rg;  // C/D row = quad*4+reg
            const int b  = mg / Pp;
            const float wsv = wsB[mg];
            float* orow = out + ((size_t)(mg + b + 1)) * Dd;   // b*197 + 1 + p
            #pragma unroll
            for (int ni = 0; ni < 4; ++ni)
                orow[n0 + wn + ni * 16 + col] = acc[mi][ni][rg] + wsv * bvv[ni];
        }
    }
}

extern "C" void kernel_launch(void* const* d_in, const int* in_sizes, int n_in,
                              void* d_out, int out_size, void* d_ws, size_t ws_size,
                              hipStream_t stream) {
    // order: x, img_ids, mask, Wq, bq, Wk, bk, Wv, bv, avgs, std_devs, noise
    const float* x       = (const float*)d_in[0];
    const int*   img_ids = (const int*)  d_in[1];
    const float* Wv      = (const float*)d_in[7];
    const float* bv      = (const float*)d_in[8];
    const float* avgs    = (const float*)d_in[9];
    const float* stds    = (const float*)d_in[10];
    const float* noise   = (const float*)d_in[11];
    float* out = (float*)d_out;

    const size_t ag_bytes  = (size_t)Bb * Pp * Dd * sizeof(unsigned short); // 19.27 MB
    const size_t wvt_bytes = (size_t)Dd * Dd * sizeof(unsigned short);      // 1.18 MB
    unsigned short* Ag  = (unsigned short*)d_ws;
    unsigned short* WvT = (unsigned short*)((char*)d_ws + ag_bytes);
    float*          wsB = (float*)((char*)d_ws + ag_bytes + wvt_bytes);

    gsa_prep<<<GATHER_BLKS + TRANS_BLKS, 256, 0, stream>>>(
        x, img_ids, Wv, avgs, stds, noise, Ag, WvT, wsB, out);
    gsa_gemm5<<<1200, 256, 0, stream>>>(Ag, WvT, wsB, bv, out);  // 8*25*6, XCD-swizzled
}